// Round 5
// baseline (296.074 us; speedup 1.0000x reference)
//
#include <hip/hip_runtime.h>
#include <hip/hip_bf16.h>

// Problem constants
#define D    1024
#define LD   64
#define NTR  8192
#define NT   8192
#define DY   128

#define SHIFT 40.0f

typedef __attribute__((ext_vector_type(8))) short bf16x8;
typedef __attribute__((ext_vector_type(4))) short short4_;
typedef __attribute__((ext_vector_type(4))) float f4;

static __device__ __forceinline__ short f2bf(float f) {
    __hip_bfloat16 h = __float2bfloat16(f);
    short s; __builtin_memcpy(&s, &h, 2); return s;
}
static __device__ __forceinline__ float bf2f(short s) {
    __hip_bfloat16 h; __builtin_memcpy(&h, &s, 2); return __bfloat162float(h);
}

// ---------------------------------------------------------------------------
// K1 (fused prep, 576 blocks):
//   blocks   0..255 : mu partial sums (atomicAdd into zeroed mu)
//   blocks 256..319 : A -> col-major bf16 hi/lo split AT[LD][D]
//   blocks 320..575 : ytr[NTR][DY] f32 -> ytrT[DY][NTR] bf16
// All three parts are independent (mu consumed only by the NEXT kernel).
// ---------------------------------------------------------------------------
__global__ __launch_bounds__(256) void prep_all(const float* __restrict__ xtr,
                                                const float* __restrict__ A,
                                                const float* __restrict__ ytr,
                                                float* __restrict__ mu,
                                                short* __restrict__ AThi,
                                                short* __restrict__ ATlo,
                                                short* __restrict__ ytrT) {
    __shared__ float tile[64][65];
    int b = blockIdx.x;
    if (b < 256) {
        int c = threadIdx.x * 4;
        int r0 = b * 32;
        f4 acc = {0.f, 0.f, 0.f, 0.f};
        #pragma unroll 4
        for (int r = 0; r < 32; ++r) {
            f4 v = *(const f4*)&xtr[(long)(r0 + r) * D + c];
            acc += v;
        }
        const float sc = 1.0f / (float)NTR;
        atomicAdd(&mu[c + 0], acc[0] * sc);
        atomicAdd(&mu[c + 1], acc[1] * sc);
        atomicAdd(&mu[c + 2], acc[2] * sc);
        atomicAdd(&mu[c + 3], acc[3] * sc);
    } else if (b < 320) {
        int k = (b - 256) * 16 + (threadIdx.x >> 4);
        int c0 = (threadIdx.x & 15) * 4;
        f4 a = *(const f4*)&A[(long)k * LD + c0];
        #pragma unroll
        for (int j = 0; j < 4; ++j) {
            int c = c0 + j;
            short hi = f2bf(a[j]);
            AThi[(long)c * D + k] = hi;
            ATlo[(long)c * D + k] = f2bf(a[j] - bf2f(hi));
        }
    } else {
        int bz = b - 320;
        int t0 = (bz & 127) * 64;
        int d0 = (bz >> 7) * 64;
        int c = threadIdx.x & 63;
        int r4 = threadIdx.x >> 6;
        #pragma unroll
        for (int i = 0; i < 16; ++i) {
            int r = i * 4 + r4;
            tile[r][c] = ytr[(long)(t0 + r) * DY + d0 + c];
        }
        __syncthreads();
        #pragma unroll
        for (int i = 0; i < 16; ++i) {
            int r = i * 4 + r4;
            ytrT[(long)(d0 + r) * NTR + t0 + c] = f2bf(tile[c][r]);
        }
    }
}

// ---------------------------------------------------------------------------
// K2: projection, LDS-free / barrier-free split-bf16 MFMA.
//   qt  = (xt - mu) @ A   (mu subtracted in f32 BEFORE the bf16 split)
//   qtr = xtr @ A         (uncentered — per-row softmax constants cancel)
// 1024 independent waves; wave gw owns 16 rows x 64 cols. A-fragments built
// in-register from x; B-fragments direct from col-major AT (L2-hot).
// ---------------------------------------------------------------------------
__global__ __launch_bounds__(256) void proj_mfma(const float* __restrict__ xt,
                                                 const float* __restrict__ xtr,
                                                 const short* __restrict__ AThi,
                                                 const short* __restrict__ ATlo,
                                                 const float* __restrict__ mu,
                                                 short* __restrict__ qt_hi,
                                                 short* __restrict__ qt_lo,
                                                 short* __restrict__ qtr_hi,
                                                 short* __restrict__ qtr_lo) {
    int tid = threadIdx.x;
    int wave = tid >> 6;
    int lane = tid & 63;
    int quad = lane >> 4;
    int l16 = lane & 15;

    int gw = blockIdx.x * 4 + wave;          // 0..1023
    int crow0 = gw * 16;
    bool is_test = crow0 < NT;
    const float* x;
    short *qh, *ql;
    int row0;
    if (is_test) { x = xt;  qh = qt_hi;  ql = qt_lo;  row0 = crow0; }
    else         { x = xtr; qh = qtr_hi; ql = qtr_lo; row0 = crow0 - NT; }
    const float msc = is_test ? 1.0f : 0.0f;

    const float* xrow = x + (long)(row0 + l16) * D + quad * 8;

    f4 acc[4];
    #pragma unroll
    for (int ct = 0; ct < 4; ++ct) acc[ct] = (f4){0.f, 0.f, 0.f, 0.f};

    #pragma unroll 2
    for (int k0 = 0; k0 < D; k0 += 64) {
        bf16x8 ah[2], al[2];
        #pragma unroll
        for (int h = 0; h < 2; ++h) {
            const float* p = xrow + k0 + h * 32;
            f4 v0 = *(const f4*)p;
            f4 v1 = *(const f4*)(p + 4);
            const float* mp = mu + k0 + h * 32 + quad * 8;
            f4 m0 = *(const f4*)mp;
            f4 m1 = *(const f4*)(mp + 4);
            v0 -= m0 * msc;
            v1 -= m1 * msc;
            #pragma unroll
            for (int e = 0; e < 4; ++e) {
                short hi0 = f2bf(v0[e]);
                short hi1 = f2bf(v1[e]);
                ah[h][e]     = hi0;
                ah[h][e + 4] = hi1;
                al[h][e]     = f2bf(v0[e] - bf2f(hi0));
                al[h][e + 4] = f2bf(v1[e] - bf2f(hi1));
            }
        }
        #pragma unroll
        for (int ct = 0; ct < 4; ++ct) {
            const short* bh = AThi + (long)(ct * 16 + l16) * D + k0 + quad * 8;
            const short* bl = ATlo + (long)(ct * 16 + l16) * D + k0 + quad * 8;
            bf16x8 bh0 = *(const bf16x8*)bh;
            bf16x8 bh1 = *(const bf16x8*)(bh + 32);
            bf16x8 bl0 = *(const bf16x8*)bl;
            bf16x8 bl1 = *(const bf16x8*)(bl + 32);
            f4 a = acc[ct];
            a = __builtin_amdgcn_mfma_f32_16x16x32_bf16(ah[0], bh0, a, 0, 0, 0);
            a = __builtin_amdgcn_mfma_f32_16x16x32_bf16(al[0], bh0, a, 0, 0, 0);
            a = __builtin_amdgcn_mfma_f32_16x16x32_bf16(ah[0], bl0, a, 0, 0, 0);
            a = __builtin_amdgcn_mfma_f32_16x16x32_bf16(ah[1], bh1, a, 0, 0, 0);
            a = __builtin_amdgcn_mfma_f32_16x16x32_bf16(al[1], bh1, a, 0, 0, 0);
            a = __builtin_amdgcn_mfma_f32_16x16x32_bf16(ah[1], bl1, a, 0, 0, 0);
            acc[ct] = a;
        }
    }

    // D layout: row = quad*4+r (x-row), col = ct*16+l16
    #pragma unroll
    for (int ct = 0; ct < 4; ++ct) {
        int col = ct * 16 + l16;
        #pragma unroll
        for (int r = 0; r < 4; ++r) {
            int grow = row0 + quad * 4 + r;
            float qv = acc[ct][r];
            short hi = f2bf(qv);
            qh[(long)grow * LD + col] = hi;
            ql[(long)grow * LD + col] = f2bf(qv - bf2f(hi));
        }
    }
}

// ---------------------------------------------------------------------------
// K3: flash attention, fixed-shift softmax, barrier-free K-loop.
// Grid 512 = 64 Q-tiles(128 rows) x 8 K-chunks(1024).  Block: 4 waves x
// 32 Q-rows.  S^T computed via swapped MFMA operands so P packs into b64
// LDS writes (2 lanes/bank).  K/V direct from global (L1/L2-resident);
// next-tile K prefetched during PV.  Merge via global fp32 atomics.
// ---------------------------------------------------------------------------
__global__ __launch_bounds__(256, 2) void flash_kernel(const short* __restrict__ qt_hi,
                                                       const short* __restrict__ qt_lo,
                                                       const short* __restrict__ qtr_hi,
                                                       const short* __restrict__ qtr_lo,
                                                       const short* __restrict__ ytrT,
                                                       float* __restrict__ Oacc,
                                                       float* __restrict__ Lacc) {
    __shared__ short ptile[4][32 * 72];   // per-wave P[q=32][t=64], pitch 72 (18.4 KB)

    int tid = threadIdx.x;
    int wave = tid >> 6;
    int lane = tid & 63;
    int quad = lane >> 4;
    int l16 = lane & 15;

    int kc = blockIdx.x & 7;              // K-chunk; blockIdx%8 -> XCD-affine
    int qi = blockIdx.x >> 3;
    int kc0 = kc * (NTR / 8);
    int q0w = qi * 128 + wave * 32;

    // Q fragments (second operand; lane holds q-row=l16, k=h*32+quad*8+j)
    bf16x8 qh[2][2], ql[2][2];
    #pragma unroll
    for (int rt = 0; rt < 2; ++rt) {
        const short* qrh = qt_hi + (long)(q0w + rt * 16 + l16) * LD + quad * 8;
        const short* qrl = qt_lo + (long)(q0w + rt * 16 + l16) * LD + quad * 8;
        qh[rt][0] = *(const bf16x8*)qrh;
        qh[rt][1] = *(const bf16x8*)(qrh + 32);
        ql[rt][0] = *(const bf16x8*)qrl;
        ql[rt][1] = *(const bf16x8*)(qrl + 32);
    }

    bf16x8 onef;
    #pragma unroll
    for (int i = 0; i < 8; ++i) onef[i] = (short)0x3F80;   // bf16(1.0)

    f4 Ov[2][8];
    f4 Lv[2];
    #pragma unroll
    for (int rt = 0; rt < 2; ++rt) {
        Lv[rt] = (f4){0.f, 0.f, 0.f, 0.f};
        #pragma unroll
        for (int jt = 0; jt < 8; ++jt) Ov[rt][jt] = (f4){0.f, 0.f, 0.f, 0.f};
    }

    short* myp = &ptile[wave][0];

    // K base pointers (first operand; lane holds t-row=l16+tile, k=quad*8+j)
    const short* khb = qtr_hi + (long)(kc0 + l16) * LD + quad * 8;
    const short* klb = qtr_lo + (long)(kc0 + l16) * LD + quad * 8;
    const short* vb  = ytrT + (long)l16 * NTR + kc0 + quad * 8;

    // preload tile 0 K fragments (tt row stride = 16*LD shorts)
    bf16x8 kh[4][2], kl[4][2];
    #pragma unroll
    for (int tt = 0; tt < 4; ++tt) {
        kh[tt][0] = *(const bf16x8*)(khb + tt * (16 * LD));
        kh[tt][1] = *(const bf16x8*)(khb + tt * (16 * LD) + 32);
        kl[tt][0] = *(const bf16x8*)(klb + tt * (16 * LD));
        kl[tt][1] = *(const bf16x8*)(klb + tt * (16 * LD) + 32);
    }

    #pragma unroll 1
    for (int it = 0; it < 16; ++it) {
        long t64 = (long)it * 64;

        // ---- S^T = K Q^T (3-term hi/lo split); D[row=t(quad*4+r)][col=q(l16)]
        f4 s[2][4];
        #pragma unroll
        for (int rt = 0; rt < 2; ++rt) {
            #pragma unroll
            for (int tt = 0; tt < 4; ++tt) {
                f4 a = (f4){0.f, 0.f, 0.f, 0.f};
                a = __builtin_amdgcn_mfma_f32_16x16x32_bf16(kh[tt][0], qh[rt][0], a, 0, 0, 0);
                a = __builtin_amdgcn_mfma_f32_16x16x32_bf16(kh[tt][0], ql[rt][0], a, 0, 0, 0);
                a = __builtin_amdgcn_mfma_f32_16x16x32_bf16(kh[tt][1], qh[rt][1], a, 0, 0, 0);
                a = __builtin_amdgcn_mfma_f32_16x16x32_bf16(kh[tt][1], ql[rt][1], a, 0, 0, 0);
                a = __builtin_amdgcn_mfma_f32_16x16x32_bf16(kl[tt][0], qh[rt][0], a, 0, 0, 0);
                a = __builtin_amdgcn_mfma_f32_16x16x32_bf16(kl[tt][1], qh[rt][1], a, 0, 0, 0);
                s[rt][tt] = a;
            }
        }

        // V (kk=0) loads — cover exp latency
        bf16x8 vf[8];
        #pragma unroll
        for (int jt = 0; jt < 8; ++jt)
            vf[jt] = *(const bf16x8*)(vb + t64 + (long)jt * (16 * NTR));

        // ---- p = exp(s-SHIFT): lane holds 4 consecutive t for col q=l16
        // store P[q][t] as one b64 per (rt,tt): addr 8B-aligned, 2 lanes/bank
        #pragma unroll
        for (int rt = 0; rt < 2; ++rt) {
            #pragma unroll
            for (int tt = 0; tt < 4; ++tt) {
                short4_ p4;
                p4[0] = f2bf(__expf(s[rt][tt][0] - SHIFT));
                p4[1] = f2bf(__expf(s[rt][tt][1] - SHIFT));
                p4[2] = f2bf(__expf(s[rt][tt][2] - SHIFT));
                p4[3] = f2bf(__expf(s[rt][tt][3] - SHIFT));
                *(short4_*)&myp[(rt * 16 + l16) * 72 + tt * 16 + quad * 4] = p4;
            }
        }

        // prefetch next tile's K (wrapped addr keeps it in-bounds)
        long koff = (long)(((it + 1) & 15)) * (64 * LD);
        #pragma unroll
        for (int tt = 0; tt < 4; ++tt) {
            kh[tt][0] = *(const bf16x8*)(khb + koff + tt * (16 * LD));
            kh[tt][1] = *(const bf16x8*)(khb + koff + tt * (16 * LD) + 32);
            kl[tt][0] = *(const bf16x8*)(klb + koff + tt * (16 * LD));
            kl[tt][1] = *(const bf16x8*)(klb + koff + tt * (16 * LD) + 32);
        }

        // ---- O += P V ; L += P @ ones   (kk = 0 then 1)
        #pragma unroll
        for (int rt = 0; rt < 2; ++rt) {
            bf16x8 pf = *(const bf16x8*)&myp[(rt * 16 + l16) * 72 + quad * 8];
            #pragma unroll
            for (int jt = 0; jt < 8; ++jt)
                Ov[rt][jt] = __builtin_amdgcn_mfma_f32_16x16x32_bf16(pf, vf[jt], Ov[rt][jt], 0, 0, 0);
            Lv[rt] = __builtin_amdgcn_mfma_f32_16x16x32_bf16(pf, onef, Lv[rt], 0, 0, 0);
        }
        #pragma unroll
        for (int jt = 0; jt < 8; ++jt)
            vf[jt] = *(const bf16x8*)(vb + t64 + 32 + (long)jt * (16 * NTR));
        #pragma unroll
        for (int rt = 0; rt < 2; ++rt) {
            bf16x8 pf = *(const bf16x8*)&myp[(rt * 16 + l16) * 72 + 32 + quad * 8];
            #pragma unroll
            for (int jt = 0; jt < 8; ++jt)
                Ov[rt][jt] = __builtin_amdgcn_mfma_f32_16x16x32_bf16(pf, vf[jt], Ov[rt][jt], 0, 0, 0);
            Lv[rt] = __builtin_amdgcn_mfma_f32_16x16x32_bf16(pf, onef, Lv[rt], 0, 0, 0);
        }
    }

    // ---- merge K-chunks via global fp32 atomics (D: row=q quad*4+r, col=dy l16)
    #pragma unroll
    for (int rt = 0; rt < 2; ++rt) {
        #pragma unroll
        for (int jt = 0; jt < 8; ++jt) {
            #pragma unroll
            for (int r = 0; r < 4; ++r)
                atomicAdd(&Oacc[(long)(q0w + rt * 16 + quad * 4 + r) * DY + jt * 16 + l16],
                          Ov[rt][jt][r]);
        }
        if (l16 == 0) {
            #pragma unroll
            for (int r = 0; r < 4; ++r)
                atomicAdd(&Lacc[q0w + rt * 16 + quad * 4 + r], Lv[rt][r]);
        }
    }
}

// ---------------------------------------------------------------------------
// K4: out = Oacc / Lacc  (row-broadcast divide)
// ---------------------------------------------------------------------------
__global__ __launch_bounds__(256) void finalize_kernel(const float* __restrict__ Oacc,
                                                       const float* __restrict__ Lacc,
                                                       float* __restrict__ out) {
    int i = (blockIdx.x * 256 + threadIdx.x) * 8;
    float linv = 1.0f / Lacc[i >> 7];
    f4 a = *(const f4*)&Oacc[i];
    f4 b = *(const f4*)&Oacc[i + 4];
    a *= linv; b *= linv;
    *(f4*)&out[i] = a;
    *(f4*)&out[i + 4] = b;
}

// ---------------------------------------------------------------------------
extern "C" void kernel_launch(void* const* d_in, const int* in_sizes, int n_in,
                              void* d_out, int out_size, void* d_ws, size_t ws_size,
                              hipStream_t stream) {
    const float* xtr = (const float*)d_in[0];   // [NTR, D]
    const float* ytr = (const float*)d_in[1];   // [NTR, DY]
    const float* xt  = (const float*)d_in[2];   // [NT, D]
    const float* A   = (const float*)d_in[3];   // [D, LD]
    float* out = (float*)d_out;                 // [NT, DY]

    // workspace carving; [mu|Lacc|Oacc] contiguous -> one memset
    char* w = (char*)d_ws;
    float* mu   = (float*)w;  w += 4096;                      // D f32
    float* Lacc = (float*)w;  w += (size_t)NT * 4;            // 32 KB
    float* Oacc = (float*)w;  w += (size_t)NT * DY * 4;       // 4 MB
    size_t mset = 4096 + (size_t)NT * 4 + (size_t)NT * DY * 4;
    short* AThi = (short*)w; w += (size_t)LD * D * 2;         // 128 KB
    short* ATlo = (short*)w; w += (size_t)LD * D * 2;
    short* qt_hi  = (short*)w; w += (size_t)NT * LD * 2;      // 1 MB each
    short* qt_lo  = (short*)w; w += (size_t)NT * LD * 2;
    short* qtr_hi = (short*)w; w += (size_t)NTR * LD * 2;
    short* qtr_lo = (short*)w; w += (size_t)NTR * LD * 2;
    short* ytrT   = (short*)w; w += (size_t)DY * NTR * 2;     // 2 MB
    (void)ws_size; (void)in_sizes; (void)n_in; (void)out_size;

    hipMemsetAsync(d_ws, 0, mset, stream);
    prep_all<<<576, 256, 0, stream>>>(xtr, A, ytr, mu, AThi, ATlo, ytrT);
    proj_mfma<<<256, 256, 0, stream>>>(xt, xtr, AThi, ATlo, mu,
                                       qt_hi, qt_lo, qtr_hi, qtr_lo);
    flash_kernel<<<512, 256, 0, stream>>>(qt_hi, qt_lo, qtr_hi, qtr_lo, ytrT,
                                          Oacc, Lacc);
    finalize_kernel<<<(NT * DY) / (256 * 8), 256, 0, stream>>>(Oacc, Lacc, out);
}

// Round 6
// 286.286 us; speedup vs baseline: 1.0342x; 1.0342x over previous
//
#include <hip/hip_runtime.h>
#include <hip/hip_bf16.h>

// Problem constants
#define D    1024
#define LD   64
#define NTR  8192
#define NT   8192
#define DY   128

#define SHIFT 40.0f
#define NCHUNK 8
#define CHUNK (NTR / NCHUNK)   // 1024

typedef __attribute__((ext_vector_type(8))) short bf16x8;
typedef __attribute__((ext_vector_type(4))) short short4_;
typedef __attribute__((ext_vector_type(4))) float f4;

static __device__ __forceinline__ short f2bf(float f) {
    __hip_bfloat16 h = __float2bfloat16(f);
    short s; __builtin_memcpy(&s, &h, 2); return s;
}
static __device__ __forceinline__ float bf2f(short s) {
    __hip_bfloat16 h; __builtin_memcpy(&h, &s, 2); return __bfloat162float(h);
}

// ---------------------------------------------------------------------------
// K1 (fused prep, 576 blocks):
//   blocks   0..255 : mu partial sums (atomicAdd into zeroed mu)
//   blocks 256..319 : A -> col-major bf16 hi/lo split AT[LD][D]
//   blocks 320..575 : ytr[NTR][DY] f32 -> ytrT[DY][NTR] bf16
// ---------------------------------------------------------------------------
__global__ __launch_bounds__(256) void prep_all(const float* __restrict__ xtr,
                                                const float* __restrict__ A,
                                                const float* __restrict__ ytr,
                                                float* __restrict__ mu,
                                                short* __restrict__ AThi,
                                                short* __restrict__ ATlo,
                                                short* __restrict__ ytrT) {
    __shared__ float tile[64][65];
    int b = blockIdx.x;
    if (b < 256) {
        int c = threadIdx.x * 4;
        int r0 = b * 32;
        f4 acc = {0.f, 0.f, 0.f, 0.f};
        #pragma unroll 4
        for (int r = 0; r < 32; ++r) {
            f4 v = *(const f4*)&xtr[(long)(r0 + r) * D + c];
            acc += v;
        }
        const float sc = 1.0f / (float)NTR;
        atomicAdd(&mu[c + 0], acc[0] * sc);
        atomicAdd(&mu[c + 1], acc[1] * sc);
        atomicAdd(&mu[c + 2], acc[2] * sc);
        atomicAdd(&mu[c + 3], acc[3] * sc);
    } else if (b < 320) {
        int k = (b - 256) * 16 + (threadIdx.x >> 4);
        int c0 = (threadIdx.x & 15) * 4;
        f4 a = *(const f4*)&A[(long)k * LD + c0];
        #pragma unroll
        for (int j = 0; j < 4; ++j) {
            int c = c0 + j;
            short hi = f2bf(a[j]);
            AThi[(long)c * D + k] = hi;
            ATlo[(long)c * D + k] = f2bf(a[j] - bf2f(hi));
        }
    } else {
        int bz = b - 320;
        int t0 = (bz & 127) * 64;
        int d0 = (bz >> 7) * 64;
        int c = threadIdx.x & 63;
        int r4 = threadIdx.x >> 6;
        #pragma unroll
        for (int i = 0; i < 16; ++i) {
            int r = i * 4 + r4;
            tile[r][c] = ytr[(long)(t0 + r) * DY + d0 + c];
        }
        __syncthreads();
        #pragma unroll
        for (int i = 0; i < 16; ++i) {
            int r = i * 4 + r4;
            ytrT[(long)(d0 + r) * NTR + t0 + c] = f2bf(tile[c][r]);
        }
    }
}

// ---------------------------------------------------------------------------
// K2: projection, LDS-free split-bf16 MFMA (unchanged from R5; passed).
//   qt  = (xt - mu) @ A ;  qtr = xtr @ A  (uncentered; constants cancel)
// ---------------------------------------------------------------------------
__global__ __launch_bounds__(256) void proj_mfma(const float* __restrict__ xt,
                                                 const float* __restrict__ xtr,
                                                 const short* __restrict__ AThi,
                                                 const short* __restrict__ ATlo,
                                                 const float* __restrict__ mu,
                                                 short* __restrict__ qt_hi,
                                                 short* __restrict__ qt_lo,
                                                 short* __restrict__ qtr_hi,
                                                 short* __restrict__ qtr_lo) {
    int tid = threadIdx.x;
    int wave = tid >> 6;
    int lane = tid & 63;
    int quad = lane >> 4;
    int l16 = lane & 15;

    int gw = blockIdx.x * 4 + wave;          // 0..1023
    int crow0 = gw * 16;
    bool is_test = crow0 < NT;
    const float* x;
    short *qh, *ql;
    int row0;
    if (is_test) { x = xt;  qh = qt_hi;  ql = qt_lo;  row0 = crow0; }
    else         { x = xtr; qh = qtr_hi; ql = qtr_lo; row0 = crow0 - NT; }
    const float msc = is_test ? 1.0f : 0.0f;

    const float* xrow = x + (long)(row0 + l16) * D + quad * 8;

    f4 acc[4];
    #pragma unroll
    for (int ct = 0; ct < 4; ++ct) acc[ct] = (f4){0.f, 0.f, 0.f, 0.f};

    #pragma unroll 2
    for (int k0 = 0; k0 < D; k0 += 64) {
        bf16x8 ah[2], al[2];
        #pragma unroll
        for (int h = 0; h < 2; ++h) {
            const float* p = xrow + k0 + h * 32;
            f4 v0 = *(const f4*)p;
            f4 v1 = *(const f4*)(p + 4);
            const float* mp = mu + k0 + h * 32 + quad * 8;
            f4 m0 = *(const f4*)mp;
            f4 m1 = *(const f4*)(mp + 4);
            v0 -= m0 * msc;
            v1 -= m1 * msc;
            #pragma unroll
            for (int e = 0; e < 4; ++e) {
                short hi0 = f2bf(v0[e]);
                short hi1 = f2bf(v1[e]);
                ah[h][e]     = hi0;
                ah[h][e + 4] = hi1;
                al[h][e]     = f2bf(v0[e] - bf2f(hi0));
                al[h][e + 4] = f2bf(v1[e] - bf2f(hi1));
            }
        }
        #pragma unroll
        for (int ct = 0; ct < 4; ++ct) {
            const short* bh = AThi + (long)(ct * 16 + l16) * D + k0 + quad * 8;
            const short* bl = ATlo + (long)(ct * 16 + l16) * D + k0 + quad * 8;
            bf16x8 bh0 = *(const bf16x8*)bh;
            bf16x8 bh1 = *(const bf16x8*)(bh + 32);
            bf16x8 bl0 = *(const bf16x8*)bl;
            bf16x8 bl1 = *(const bf16x8*)(bl + 32);
            f4 a = acc[ct];
            a = __builtin_amdgcn_mfma_f32_16x16x32_bf16(ah[0], bh0, a, 0, 0, 0);
            a = __builtin_amdgcn_mfma_f32_16x16x32_bf16(al[0], bh0, a, 0, 0, 0);
            a = __builtin_amdgcn_mfma_f32_16x16x32_bf16(ah[0], bl0, a, 0, 0, 0);
            a = __builtin_amdgcn_mfma_f32_16x16x32_bf16(ah[1], bh1, a, 0, 0, 0);
            a = __builtin_amdgcn_mfma_f32_16x16x32_bf16(al[1], bh1, a, 0, 0, 0);
            a = __builtin_amdgcn_mfma_f32_16x16x32_bf16(ah[1], bl1, a, 0, 0, 0);
            acc[ct] = a;
        }
    }

    #pragma unroll
    for (int ct = 0; ct < 4; ++ct) {
        int col = ct * 16 + l16;
        #pragma unroll
        for (int r = 0; r < 4; ++r) {
            int grow = row0 + quad * 4 + r;
            float qv = acc[ct][r];
            short hi = f2bf(qv);
            qh[(long)grow * LD + col] = hi;
            ql[(long)grow * LD + col] = f2bf(qv - bf2f(hi));
        }
    }
}

// ---------------------------------------------------------------------------
// K3: flash attention.  Grid 512 = 64 Q-tiles(128 rows) x 8 K-chunks(1024).
// 32-row K tiles, 32 iters.  K/V direct from global (co-resident blocks
// share kc -> L1/L2 hits).  K register double-buffer; strict FIFO load
// order so every wait targets loads issued >= ~1 iter earlier.  LDS only
// for the P round-trip (b64 stores / b128 reads, 2-way banks = free).
// No atomics: per-chunk partial O/L written to Opart/Lpart.
// ---------------------------------------------------------------------------
__global__ __launch_bounds__(256, 2) void flash_kernel(const short* __restrict__ qt_hi,
                                                       const short* __restrict__ qt_lo,
                                                       const short* __restrict__ qtr_hi,
                                                       const short* __restrict__ qtr_lo,
                                                       const short* __restrict__ ytrT,
                                                       float* __restrict__ Opart,
                                                       float* __restrict__ Lpart) {
    __shared__ short ptile[4][32 * 40];   // per-wave P[q=32][t=32], pitch 40 (10 KB)

    int tid = threadIdx.x;
    int wave = tid >> 6;
    int lane = tid & 63;
    int quad = lane >> 4;
    int l16 = lane & 15;

    int kc = blockIdx.x & 7;              // blockIdx%8 -> XCD-affine
    int qi = blockIdx.x >> 3;
    int kc0 = kc * CHUNK;
    int q0w = qi * 128 + wave * 32;

    // Q fragments (B-operand for S^T: lane q-row=l16, k=h*32+quad*8+j)
    bf16x8 qh[2][2], ql[2][2];
    #pragma unroll
    for (int rt = 0; rt < 2; ++rt) {
        const short* qrh = qt_hi + (long)(q0w + rt * 16 + l16) * LD + quad * 8;
        const short* qrl = qt_lo + (long)(q0w + rt * 16 + l16) * LD + quad * 8;
        qh[rt][0] = *(const bf16x8*)qrh;
        qh[rt][1] = *(const bf16x8*)(qrh + 32);
        ql[rt][0] = *(const bf16x8*)qrl;
        ql[rt][1] = *(const bf16x8*)(qrl + 32);
    }

    bf16x8 onef;
    #pragma unroll
    for (int i = 0; i < 8; ++i) onef[i] = (short)0x3F80;   // bf16(1.0)

    f4 Ov[2][8];
    f4 Lv[2];
    #pragma unroll
    for (int rt = 0; rt < 2; ++rt) {
        Lv[rt] = (f4){0.f, 0.f, 0.f, 0.f};
        #pragma unroll
        for (int jt = 0; jt < 8; ++jt) Ov[rt][jt] = (f4){0.f, 0.f, 0.f, 0.f};
    }

    short* myp = &ptile[wave][0];

    // base pointers
    const short* khb = qtr_hi + (long)(kc0 + l16) * LD + quad * 8;
    const short* klb = qtr_lo + (long)(kc0 + l16) * LD + quad * 8;
    const short* vb  = ytrT + (long)l16 * NTR + kc0 + quad * 8;

    // K fragment double buffer: [buf][tt][khalf]
    bf16x8 kh[2][2][2], kl[2][2][2];

    // preload tile 0 into buf 0
    #pragma unroll
    for (int tt = 0; tt < 2; ++tt) {
        #pragma unroll
        for (int h2 = 0; h2 < 2; ++h2) {
            kh[0][tt][h2] = *(const bf16x8*)(khb + (long)tt * (16 * LD) + h2 * 32);
            kl[0][tt][h2] = *(const bf16x8*)(klb + (long)tt * (16 * LD) + h2 * 32);
        }
    }

#define FLASH_ITER(CUR, IT)                                                          \
    {                                                                                \
        long t32 = (long)(IT) * 32;                                                  \
        /* V(i) loads — consumed ~250 cyc later by PV */                             \
        bf16x8 vf[8];                                                                \
        _Pragma("unroll")                                                            \
        for (int jt = 0; jt < 8; ++jt)                                               \
            vf[jt] = *(const bf16x8*)(vb + t32 + (long)jt * (16 * NTR));             \
        /* K(i+1) prefetch into the other buffer (wrapped in-bounds) */              \
        {                                                                            \
            long koff = (long)(((IT) + 1) & 31) * (32 * LD);                         \
            _Pragma("unroll")                                                        \
            for (int tt = 0; tt < 2; ++tt) {                                         \
                _Pragma("unroll")                                                    \
                for (int h2 = 0; h2 < 2; ++h2) {                                     \
                    kh[1 - (CUR)][tt][h2] =                                          \
                        *(const bf16x8*)(khb + koff + (long)tt * (16 * LD) + h2 * 32); \
                    kl[1 - (CUR)][tt][h2] =                                          \
                        *(const bf16x8*)(klb + koff + (long)tt * (16 * LD) + h2 * 32); \
                }                                                                    \
            }                                                                        \
        }                                                                            \
        /* S^T = K Q^T (3-term hi/lo); waits only on K(i) (issued last iter) */      \
        f4 s[2][2];                                                                  \
        _Pragma("unroll")                                                            \
        for (int rt = 0; rt < 2; ++rt) {                                             \
            _Pragma("unroll")                                                        \
            for (int tt = 0; tt < 2; ++tt) {                                         \
                f4 a = (f4){0.f, 0.f, 0.f, 0.f};                                     \
                a = __builtin_amdgcn_mfma_f32_16x16x32_bf16(kh[CUR][tt][0], qh[rt][0], a, 0, 0, 0); \
                a = __builtin_amdgcn_mfma_f32_16x16x32_bf16(kh[CUR][tt][0], ql[rt][0], a, 0, 0, 0); \
                a = __builtin_amdgcn_mfma_f32_16x16x32_bf16(kh[CUR][tt][1], qh[rt][1], a, 0, 0, 0); \
                a = __builtin_amdgcn_mfma_f32_16x16x32_bf16(kh[CUR][tt][1], ql[rt][1], a, 0, 0, 0); \
                a = __builtin_amdgcn_mfma_f32_16x16x32_bf16(kl[CUR][tt][0], qh[rt][0], a, 0, 0, 0); \
                a = __builtin_amdgcn_mfma_f32_16x16x32_bf16(kl[CUR][tt][1], qh[rt][1], a, 0, 0, 0); \
                s[rt][tt] = a;                                                       \
            }                                                                        \
        }                                                                            \
        /* p = exp(s-SHIFT); lane holds 4 consecutive t for q=l16 -> b64 store */    \
        _Pragma("unroll")                                                            \
        for (int rt = 0; rt < 2; ++rt) {                                             \
            _Pragma("unroll")                                                        \
            for (int tt = 0; tt < 2; ++tt) {                                         \
                short4_ p4;                                                          \
                p4[0] = f2bf(__expf(s[rt][tt][0] - SHIFT));                          \
                p4[1] = f2bf(__expf(s[rt][tt][1] - SHIFT));                          \
                p4[2] = f2bf(__expf(s[rt][tt][2] - SHIFT));                          \
                p4[3] = f2bf(__expf(s[rt][tt][3] - SHIFT));                          \
                *(short4_*)&myp[(rt * 16 + l16) * 40 + tt * 16 + quad * 4] = p4;     \
            }                                                                        \
        }                                                                            \
        /* O += P V ; L += P @ ones  (PV waits only on V(i)) */                      \
        _Pragma("unroll")                                                            \
        for (int rt = 0; rt < 2; ++rt) {                                             \
            bf16x8 pf = *(const bf16x8*)&myp[(rt * 16 + l16) * 40 + quad * 8];       \
            _Pragma("unroll")                                                        \
            for (int jt = 0; jt < 8; ++jt)                                           \
                Ov[rt][jt] = __builtin_amdgcn_mfma_f32_16x16x32_bf16(pf, vf[jt], Ov[rt][jt], 0, 0, 0); \
            Lv[rt] = __builtin_amdgcn_mfma_f32_16x16x32_bf16(pf, onef, Lv[rt], 0, 0, 0); \
        }                                                                            \
    }

    #pragma unroll 1
    for (int it2 = 0; it2 < 16; ++it2) {
        FLASH_ITER(0, 2 * it2)
        FLASH_ITER(1, 2 * it2 + 1)
    }
#undef FLASH_ITER

    // ---- per-chunk partial outputs (plain coalesced stores, no atomics) ----
    long ob = (long)kc * NT;
    #pragma unroll
    for (int rt = 0; rt < 2; ++rt) {
        #pragma unroll
        for (int jt = 0; jt < 8; ++jt) {
            #pragma unroll
            for (int r = 0; r < 4; ++r)
                Opart[(ob + q0w + rt * 16 + quad * 4 + r) * DY + jt * 16 + l16] =
                    Ov[rt][jt][r];
        }
        if (l16 == 0) {
            #pragma unroll
            for (int r = 0; r < 4; ++r)
                Lpart[ob + q0w + rt * 16 + quad * 4 + r] = Lv[rt][r];
        }
    }
}

// ---------------------------------------------------------------------------
// K4: out[q][dy] = sum_kc Opart[kc][q][dy] / sum_kc Lpart[kc][q]
// ---------------------------------------------------------------------------
__global__ __launch_bounds__(256) void finalize_kernel(const float* __restrict__ Opart,
                                                       const float* __restrict__ Lpart,
                                                       float* __restrict__ out) {
    long i = ((long)blockIdx.x * 256 + threadIdx.x) * 8;
    long row = i >> 7;          // DY = 128
    float L = 0.f;
    f4 a = (f4){0.f, 0.f, 0.f, 0.f};
    f4 b = (f4){0.f, 0.f, 0.f, 0.f};
    #pragma unroll
    for (int kc = 0; kc < NCHUNK; ++kc) {
        L += Lpart[(long)kc * NT + row];
        const float* p = &Opart[((long)kc * NT) * DY + i];
        a += *(const f4*)p;
        b += *(const f4*)(p + 4);
    }
    float linv = 1.0f / L;
    a *= linv; b *= linv;
    *(f4*)&out[i] = a;
    *(f4*)&out[i + 4] = b;
}

// ---------------------------------------------------------------------------
extern "C" void kernel_launch(void* const* d_in, const int* in_sizes, int n_in,
                              void* d_out, int out_size, void* d_ws, size_t ws_size,
                              hipStream_t stream) {
    const float* xtr = (const float*)d_in[0];   // [NTR, D]
    const float* ytr = (const float*)d_in[1];   // [NTR, DY]
    const float* xt  = (const float*)d_in[2];   // [NT, D]
    const float* A   = (const float*)d_in[3];   // [D, LD]
    float* out = (float*)d_out;                 // [NT, DY]

    // workspace carving
    char* w = (char*)d_ws;
    float* mu    = (float*)w; w += 4096;                          // D f32 (memset)
    float* Lpart = (float*)w; w += (size_t)NCHUNK * NT * 4;       // 256 KB
    float* Opart = (float*)w; w += (size_t)NCHUNK * NT * DY * 4;  // 32 MB
    short* AThi  = (short*)w; w += (size_t)LD * D * 2;            // 128 KB
    short* ATlo  = (short*)w; w += (size_t)LD * D * 2;
    short* qt_hi  = (short*)w; w += (size_t)NT * LD * 2;          // 1 MB each
    short* qt_lo  = (short*)w; w += (size_t)NT * LD * 2;
    short* qtr_hi = (short*)w; w += (size_t)NTR * LD * 2;
    short* qtr_lo = (short*)w; w += (size_t)NTR * LD * 2;
    short* ytrT   = (short*)w; w += (size_t)DY * NTR * 2;         // 2 MB
    (void)ws_size; (void)in_sizes; (void)n_in; (void)out_size;

    hipMemsetAsync(mu, 0, 4096, stream);
    prep_all<<<576, 256, 0, stream>>>(xtr, A, ytr, mu, AThi, ATlo, ytrT);
    proj_mfma<<<256, 256, 0, stream>>>(xt, xtr, AThi, ATlo, mu,
                                       qt_hi, qt_lo, qtr_hi, qtr_lo);
    flash_kernel<<<512, 256, 0, stream>>>(qt_hi, qt_lo, qtr_hi, qtr_lo, ytrT,
                                          Opart, Lpart);
    finalize_kernel<<<(NT * DY) / (256 * 8), 256, 0, stream>>>(Opart, Lpart, out);
}

// Round 7
// 211.528 us; speedup vs baseline: 1.3997x; 1.3534x over previous
//
#include <hip/hip_runtime.h>
#include <hip/hip_bf16.h>

// Problem constants
#define D    1024
#define LD   64
#define NTR  8192
#define NT   8192
#define DY   128

#define SHIFT 40.0f
#define NCHUNK 8
#define CHUNK (NTR / NCHUNK)   // 1024 train rows per chunk, 32 tiles of 32

typedef __attribute__((ext_vector_type(8))) short bf16x8;
typedef __attribute__((ext_vector_type(4))) short short4_;
typedef __attribute__((ext_vector_type(4))) float f4;

static __device__ __forceinline__ short f2bf(float f) {
    __hip_bfloat16 h = __float2bfloat16(f);
    short s; __builtin_memcpy(&s, &h, 2); return s;
}
static __device__ __forceinline__ float bf2f(short s) {
    __hip_bfloat16 h; __builtin_memcpy(&h, &s, 2); return __bfloat162float(h);
}

// async global->LDS DMA, 16 B per lane: LDS dest = uniform base + lane*16
static __device__ __forceinline__ void gload_lds16(const short* g, short* l) {
    __builtin_amdgcn_global_load_lds(
        (const __attribute__((address_space(1))) unsigned int*)g,
        (__attribute__((address_space(3))) unsigned int*)l,
        16, 0, 0);
}

// ---------------------------------------------------------------------------
// K1 (fused prep, 576 blocks):
//   blocks   0..255 : mu partial sums (atomicAdd into zeroed mu)
//   blocks 256..319 : A -> col-major bf16 hi/lo split AT[LD][D]
//   blocks 320..575 : ytr[NTR][DY] f32 -> V tiles: [tile32][dy][32] bf16,
//                     16B chunks swizzled:  pos = (tloc>>3) ^ (dy&3)
// ---------------------------------------------------------------------------
__global__ __launch_bounds__(256) void prep_all(const float* __restrict__ xtr,
                                                const float* __restrict__ A,
                                                const float* __restrict__ ytr,
                                                float* __restrict__ mu,
                                                short* __restrict__ AThi,
                                                short* __restrict__ ATlo,
                                                short* __restrict__ vtile) {
    __shared__ float tile[64][65];
    int b = blockIdx.x;
    if (b < 256) {
        int c = threadIdx.x * 4;
        int r0 = b * 32;
        f4 acc = {0.f, 0.f, 0.f, 0.f};
        #pragma unroll 4
        for (int r = 0; r < 32; ++r) {
            f4 v = *(const f4*)&xtr[(long)(r0 + r) * D + c];
            acc += v;
        }
        const float sc = 1.0f / (float)NTR;
        atomicAdd(&mu[c + 0], acc[0] * sc);
        atomicAdd(&mu[c + 1], acc[1] * sc);
        atomicAdd(&mu[c + 2], acc[2] * sc);
        atomicAdd(&mu[c + 3], acc[3] * sc);
    } else if (b < 320) {
        int k = (b - 256) * 16 + (threadIdx.x >> 4);
        int c0 = (threadIdx.x & 15) * 4;
        f4 a = *(const f4*)&A[(long)k * LD + c0];
        #pragma unroll
        for (int j = 0; j < 4; ++j) {
            int c = c0 + j;
            short hi = f2bf(a[j]);
            AThi[(long)c * D + k] = hi;
            ATlo[(long)c * D + k] = f2bf(a[j] - bf2f(hi));
        }
    } else {
        int bz = b - 320;
        int t0 = (bz & 127) * 64;
        int d0 = (bz >> 7) * 64;
        int c = threadIdx.x & 63;
        int r4 = threadIdx.x >> 6;
        #pragma unroll
        for (int i = 0; i < 16; ++i) {
            int r = i * 4 + r4;
            tile[r][c] = ytr[(long)(t0 + r) * DY + d0 + c];
        }
        __syncthreads();
        #pragma unroll
        for (int i = 0; i < 16; ++i) {
            int r = i * 4 + r4;       // dy local
            int t = t0 + c;
            int dy = d0 + r;
            long idx = (long)(t >> 5) * 4096 + (long)dy * 32
                     + ((((t >> 3) & 3) ^ (dy & 3)) << 3) + (t & 7);
            vtile[idx] = f2bf(tile[c][r]);
        }
    }
}

// ---------------------------------------------------------------------------
// K2: projection, LDS-free split-bf16 MFMA with depth-1 double-buffered
// prefetch of x and AT (1 wave/SIMD -> ILP is the only latency hiding).
//   qt  = (xt - mu) @ A  -> linear [NT][64] hi/lo
//   qtr = xtr @ A        -> SWIZZLED 32-row tiles: [tile][tl][64],
//                           16B chunk pos = (k>>3) ^ (tl&7)
// ---------------------------------------------------------------------------
__global__ __launch_bounds__(256, 1) void proj_mfma(const float* __restrict__ xt,
                                                    const float* __restrict__ xtr,
                                                    const short* __restrict__ AThi,
                                                    const short* __restrict__ ATlo,
                                                    const float* __restrict__ mu,
                                                    short* __restrict__ qt_hi,
                                                    short* __restrict__ qt_lo,
                                                    short* __restrict__ ktr_hi,
                                                    short* __restrict__ ktr_lo) {
    int tid = threadIdx.x;
    int wave = tid >> 6;
    int lane = tid & 63;
    int quad = lane >> 4;
    int l16 = lane & 15;

    int gw = blockIdx.x * 4 + wave;          // 0..1023
    int crow0 = gw * 16;
    bool is_test = crow0 < NT;
    const float* x = is_test ? xt : xtr;
    int row0 = is_test ? crow0 : crow0 - NT;
    const float msc = is_test ? 1.0f : 0.0f;

    const float* xrow = x + (long)(row0 + l16) * D + quad * 8;
    const short* bhrow = AThi + (long)l16 * D + quad * 8;   // + ct*16*D + k0 + h*32
    const short* blrow = ATlo + (long)l16 * D + quad * 8;

    f4 acc[4];
    #pragma unroll
    for (int ct = 0; ct < 4; ++ct) acc[ct] = (f4){0.f, 0.f, 0.f, 0.f};

    f4 xv[2][4];
    bf16x8 bh[2][8], bl[2][8];

#define PROJ_LOAD(B, K0)                                                        \
    {                                                                           \
        long kw = (K0) & (D - 1);                                               \
        _Pragma("unroll")                                                       \
        for (int h = 0; h < 2; ++h) {                                           \
            xv[B][h * 2 + 0] = *(const f4*)(xrow + kw + h * 32);                \
            xv[B][h * 2 + 1] = *(const f4*)(xrow + kw + h * 32 + 4);            \
        }                                                                       \
        _Pragma("unroll")                                                       \
        for (int ct = 0; ct < 4; ++ct) {                                        \
            _Pragma("unroll")                                                   \
            for (int h = 0; h < 2; ++h) {                                       \
                bh[B][ct * 2 + h] = *(const bf16x8*)(bhrow + (long)ct * 16 * D + kw + h * 32); \
                bl[B][ct * 2 + h] = *(const bf16x8*)(blrow + (long)ct * 16 * D + kw + h * 32); \
            }                                                                   \
        }                                                                       \
    }

#define PROJ_COMP(B, K0)                                                        \
    {                                                                           \
        bf16x8 ah[2], al[2];                                                    \
        _Pragma("unroll")                                                       \
        for (int h = 0; h < 2; ++h) {                                           \
            f4 v0 = xv[B][h * 2 + 0];                                           \
            f4 v1 = xv[B][h * 2 + 1];                                           \
            const float* mp = mu + (K0) + h * 32 + quad * 8;                    \
            f4 m0 = *(const f4*)mp;                                             \
            f4 m1 = *(const f4*)(mp + 4);                                       \
            v0 -= m0 * msc;                                                     \
            v1 -= m1 * msc;                                                     \
            _Pragma("unroll")                                                   \
            for (int e = 0; e < 4; ++e) {                                       \
                short hi0 = f2bf(v0[e]);                                        \
                short hi1 = f2bf(v1[e]);                                        \
                ah[h][e]     = hi0;                                             \
                ah[h][e + 4] = hi1;                                             \
                al[h][e]     = f2bf(v0[e] - bf2f(hi0));                         \
                al[h][e + 4] = f2bf(v1[e] - bf2f(hi1));                         \
            }                                                                   \
        }                                                                       \
        _Pragma("unroll")                                                       \
        for (int ct = 0; ct < 4; ++ct) {                                        \
            f4 a = acc[ct];                                                     \
            a = __builtin_amdgcn_mfma_f32_16x16x32_bf16(ah[0], bh[B][ct*2+0], a, 0, 0, 0); \
            a = __builtin_amdgcn_mfma_f32_16x16x32_bf16(al[0], bh[B][ct*2+0], a, 0, 0, 0); \
            a = __builtin_amdgcn_mfma_f32_16x16x32_bf16(ah[0], bl[B][ct*2+0], a, 0, 0, 0); \
            a = __builtin_amdgcn_mfma_f32_16x16x32_bf16(ah[1], bh[B][ct*2+1], a, 0, 0, 0); \
            a = __builtin_amdgcn_mfma_f32_16x16x32_bf16(al[1], bh[B][ct*2+1], a, 0, 0, 0); \
            a = __builtin_amdgcn_mfma_f32_16x16x32_bf16(ah[1], bl[B][ct*2+1], a, 0, 0, 0); \
            acc[ct] = a;                                                        \
        }                                                                       \
    }

    PROJ_LOAD(0, 0)
    #pragma unroll 1
    for (int kk2 = 0; kk2 < 8; ++kk2) {
        int k0 = kk2 * 128;
        PROJ_LOAD(1, k0 + 64)
        PROJ_COMP(0, k0)
        PROJ_LOAD(0, k0 + 128)     // wraps to 0 on last iter (data unused)
        PROJ_COMP(1, k0 + 64)
    }
#undef PROJ_LOAD
#undef PROJ_COMP

    // D layout: row = quad*4+r (x-row), col = ct*16+l16
    #pragma unroll
    for (int ct = 0; ct < 4; ++ct) {
        int col = ct * 16 + l16;
        #pragma unroll
        for (int r = 0; r < 4; ++r) {
            int grow = row0 + quad * 4 + r;
            float qv = acc[ct][r];
            short hi = f2bf(qv);
            short lo = f2bf(qv - bf2f(hi));
            if (is_test) {
                qt_hi[(long)grow * LD + col] = hi;
                qt_lo[(long)grow * LD + col] = lo;
            } else {
                int tl = grow & 31;
                long idx = (long)(grow >> 5) * 2048 + tl * 64
                         + ((((col >> 3) ^ (tl & 7))) << 3) + (col & 7);
                ktr_hi[idx] = hi;
                ktr_lo[idx] = lo;
            }
        }
    }
}

// ---------------------------------------------------------------------------
// K3: flash attention, m97-style LDS staging.
// Grid 512 = 64 Q-tiles(128 rows) x 8 K-chunks(1024).  32-row t-tiles.
// K(hi,lo)+V staged per block via global_load_lds (async DMA), double-
// buffered, ONE barrier per iter.  Swizzled tile layouts give conflict-free
// b128 fragment reads.  S^T via swapped operands -> P packs to b64 stores.
// Merge across chunks via per-chunk partial stores (no atomics).
// ---------------------------------------------------------------------------
__global__ __launch_bounds__(256, 2) void flash_kernel(const short* __restrict__ qt_hi,
                                                       const short* __restrict__ qt_lo,
                                                       const short* __restrict__ ksw_hi,
                                                       const short* __restrict__ ksw_lo,
                                                       const short* __restrict__ vtile,
                                                       float* __restrict__ Opart,
                                                       float* __restrict__ Lpart) {
    __shared__ __align__(16) short kbh[2][2048];    //  8 KB  K-hi tiles
    __shared__ __align__(16) short kbl[2][2048];    //  8 KB  K-lo tiles
    __shared__ __align__(16) short vbuf[2][4096];   // 16 KB  V tiles
    __shared__ __align__(16) short ptile[4][1280];  // 10 KB  per-wave P[32][32] pitch 40

    int tid = threadIdx.x;
    int wave = tid >> 6;
    int lane = tid & 63;
    int quad = lane >> 4;
    int l16 = lane & 15;

    int kc = blockIdx.x & 7;              // blockIdx%8 -> XCD-affine chunk
    int qi = blockIdx.x >> 3;
    int q0w = qi * 128 + wave * 32;
    int tile0 = kc * 32;

    int soff = wave * 512 + lane * 8;     // staging src offset (shorts)
    int ldso = wave * 512;                // staging LDS base (shorts, wave-uniform)

    // Q fragments (B-operand for S^T: lane q-row=l16, k=h*32+quad*8+j)
    bf16x8 qh[2][2], ql[2][2];
    #pragma unroll
    for (int rt = 0; rt < 2; ++rt) {
        const short* qrh = qt_hi + (long)(q0w + rt * 16 + l16) * LD + quad * 8;
        const short* qrl = qt_lo + (long)(q0w + rt * 16 + l16) * LD + quad * 8;
        qh[rt][0] = *(const bf16x8*)qrh;
        qh[rt][1] = *(const bf16x8*)(qrh + 32);
        ql[rt][0] = *(const bf16x8*)qrl;
        ql[rt][1] = *(const bf16x8*)(qrl + 32);
    }

    bf16x8 onef;
    #pragma unroll
    for (int i = 0; i < 8; ++i) onef[i] = (short)0x3F80;   // bf16(1.0)

    f4 Ov[2][8];
    f4 Lv[2];
    #pragma unroll
    for (int rt = 0; rt < 2; ++rt) {
        Lv[rt] = (f4){0.f, 0.f, 0.f, 0.f};
        #pragma unroll
        for (int jt = 0; jt < 8; ++jt) Ov[rt][jt] = (f4){0.f, 0.f, 0.f, 0.f};
    }

    short* myp = &ptile[wave][0];
    const int p0 = ((quad ^ (l16 & 7)) << 3);          // K chunk pos (h2=0); h2=1 -> p0^32
    const int pv = ((quad ^ (l16 & 3)) << 3);          // V chunk pos

    // stage tile 0 into buf 0
    gload_lds16(ksw_hi + (long)tile0 * 2048 + soff, &kbh[0][ldso]);
    gload_lds16(ksw_lo + (long)tile0 * 2048 + soff, &kbl[0][ldso]);
    gload_lds16(vtile + (long)tile0 * 4096 + soff, &vbuf[0][ldso]);
    gload_lds16(vtile + (long)tile0 * 4096 + 2048 + soff, &vbuf[0][2048 + ldso]);
    __syncthreads();

    #pragma unroll 1
    for (int it = 0; it < 32; ++it) {
        int cur = it & 1;
        if (it < 31) {
            int nb = cur ^ 1;
            long tb = (long)(tile0 + it + 1);
            gload_lds16(ksw_hi + tb * 2048 + soff, &kbh[nb][ldso]);
            gload_lds16(ksw_lo + tb * 2048 + soff, &kbl[nb][ldso]);
            gload_lds16(vtile + tb * 4096 + soff, &vbuf[nb][ldso]);
            gload_lds16(vtile + tb * 4096 + 2048 + soff, &vbuf[nb][2048 + ldso]);
        }

        // ---- K fragments from LDS (shared by all 4 waves) ----
        bf16x8 kh[2][2], kl[2][2];         // [tt][h2]
        #pragma unroll
        for (int tt = 0; tt < 2; ++tt) {
            int rb = (tt * 16 + l16) * 64;
            kh[tt][0] = *(const bf16x8*)&kbh[cur][rb + p0];
            kh[tt][1] = *(const bf16x8*)&kbh[cur][rb + (p0 ^ 32)];
            kl[tt][0] = *(const bf16x8*)&kbl[cur][rb + p0];
            kl[tt][1] = *(const bf16x8*)&kbl[cur][rb + (p0 ^ 32)];
        }

        // ---- S^T = K Q^T (3-term hi/lo); D[row=t(quad*4+r)][col=q(l16)] ----
        f4 s[2][2];
        #pragma unroll
        for (int rt = 0; rt < 2; ++rt) {
            #pragma unroll
            for (int tt = 0; tt < 2; ++tt) {
                f4 a = (f4){0.f, 0.f, 0.f, 0.f};
                a = __builtin_amdgcn_mfma_f32_16x16x32_bf16(kh[tt][0], qh[rt][0], a, 0, 0, 0);
                a = __builtin_amdgcn_mfma_f32_16x16x32_bf16(kh[tt][0], ql[rt][0], a, 0, 0, 0);
                a = __builtin_amdgcn_mfma_f32_16x16x32_bf16(kh[tt][1], qh[rt][1], a, 0, 0, 0);
                a = __builtin_amdgcn_mfma_f32_16x16x32_bf16(kh[tt][1], ql[rt][1], a, 0, 0, 0);
                a = __builtin_amdgcn_mfma_f32_16x16x32_bf16(kl[tt][0], qh[rt][0], a, 0, 0, 0);
                a = __builtin_amdgcn_mfma_f32_16x16x32_bf16(kl[tt][1], qh[rt][1], a, 0, 0, 0);
                s[rt][tt] = a;
            }
        }

        // ---- p = exp(s-SHIFT); lane holds 4 consecutive t for q=l16 -> b64
        #pragma unroll
        for (int rt = 0; rt < 2; ++rt) {
            #pragma unroll
            for (int tt = 0; tt < 2; ++tt) {
                short4_ p4;
                p4[0] = f2bf(__expf(s[rt][tt][0] - SHIFT));
                p4[1] = f2bf(__expf(s[rt][tt][1] - SHIFT));
                p4[2] = f2bf(__expf(s[rt][tt][2] - SHIFT));
                p4[3] = f2bf(__expf(s[rt][tt][3] - SHIFT));
                *(short4_*)&myp[(rt * 16 + l16) * 40 + tt * 16 + quad * 4] = p4;
            }
        }

        // ---- V fragments + O += P V ; L += P @ ones ----
        bf16x8 vf[8];
        #pragma unroll
        for (int jt = 0; jt < 8; ++jt)
            vf[jt] = *(const bf16x8*)&vbuf[cur][(jt * 16 + l16) * 32 + pv];
        #pragma unroll
        for (int rt = 0; rt < 2; ++rt) {
            bf16x8 pf = *(const bf16x8*)&myp[(rt * 16 + l16) * 40 + quad * 8];
            #pragma unroll
            for (int jt = 0; jt < 8; ++jt)
                Ov[rt][jt] = __builtin_amdgcn_mfma_f32_16x16x32_bf16(pf, vf[jt], Ov[rt][jt], 0, 0, 0);
            Lv[rt] = __builtin_amdgcn_mfma_f32_16x16x32_bf16(pf, onef, Lv[rt], 0, 0, 0);
        }

        __syncthreads();   // drains DMA (next buf ready) + all LDS reads done
    }

    // ---- per-chunk partial outputs (plain coalesced stores, no atomics) ----
    long ob = (long)kc * NT;
    #pragma unroll
    for (int rt = 0; rt < 2; ++rt) {
        #pragma unroll
        for (int jt = 0; jt < 8; ++jt) {
            #pragma unroll
            for (int r = 0; r < 4; ++r)
                Opart[(ob + q0w + rt * 16 + quad * 4 + r) * DY + jt * 16 + l16] =
                    Ov[rt][jt][r];
        }
        if (l16 == 0) {
            #pragma unroll
            for (int r = 0; r < 4; ++r)
                Lpart[ob + q0w + rt * 16 + quad * 4 + r] = Lv[rt][r];
        }
    }
}

// ---------------------------------------------------------------------------
// K4: out[q][dy] = sum_kc Opart[kc][q][dy] / sum_kc Lpart[kc][q]
// ---------------------------------------------------------------------------
__global__ __launch_bounds__(256) void finalize_kernel(const float* __restrict__ Opart,
                                                       const float* __restrict__ Lpart,
                                                       float* __restrict__ out) {
    long i = ((long)blockIdx.x * 256 + threadIdx.x) * 8;
    long row = i >> 7;          // DY = 128
    float L = 0.f;
    f4 a = (f4){0.f, 0.f, 0.f, 0.f};
    f4 b = (f4){0.f, 0.f, 0.f, 0.f};
    #pragma unroll
    for (int kc = 0; kc < NCHUNK; ++kc) {
        L += Lpart[(long)kc * NT + row];
        const float* p = &Opart[((long)kc * NT) * DY + i];
        a += *(const f4*)p;
        b += *(const f4*)(p + 4);
    }
    float linv = 1.0f / L;
    a *= linv; b *= linv;
    *(f4*)&out[i] = a;
    *(f4*)&out[i + 4] = b;
}

// ---------------------------------------------------------------------------
extern "C" void kernel_launch(void* const* d_in, const int* in_sizes, int n_in,
                              void* d_out, int out_size, void* d_ws, size_t ws_size,
                              hipStream_t stream) {
    const float* xtr = (const float*)d_in[0];   // [NTR, D]
    const float* ytr = (const float*)d_in[1];   // [NTR, DY]
    const float* xt  = (const float*)d_in[2];   // [NT, D]
    const float* A   = (const float*)d_in[3];   // [D, LD]
    float* out = (float*)d_out;                 // [NT, DY]

    // workspace carving
    char* w = (char*)d_ws;
    float* mu    = (float*)w; w += 4096;                          // D f32 (memset)
    float* Lpart = (float*)w; w += (size_t)NCHUNK * NT * 4;       // 256 KB
    float* Opart = (float*)w; w += (size_t)NCHUNK * NT * DY * 4;  // 32 MB
    short* AThi  = (short*)w; w += (size_t)LD * D * 2;            // 128 KB
    short* ATlo  = (short*)w; w += (size_t)LD * D * 2;
    short* qt_hi  = (short*)w; w += (size_t)NT * LD * 2;          // 1 MB each
    short* qt_lo  = (short*)w; w += (size_t)NT * LD * 2;
    short* ksw_hi = (short*)w; w += (size_t)NTR * LD * 2;         // swizzled tiles
    short* ksw_lo = (short*)w; w += (size_t)NTR * LD * 2;
    short* vtile  = (short*)w; w += (size_t)DY * NTR * 2;         // 2 MB swizzled tiles
    (void)ws_size; (void)in_sizes; (void)n_in; (void)out_size;

    hipMemsetAsync(mu, 0, 4096, stream);
    prep_all<<<576, 256, 0, stream>>>(xtr, A, ytr, mu, AThi, ATlo, vtile);
    proj_mfma<<<256, 256, 0, stream>>>(xt, xtr, AThi, ATlo, mu,
                                       qt_hi, qt_lo, ksw_hi, ksw_lo);
    flash_kernel<<<512, 256, 0, stream>>>(qt_hi, qt_lo, ksw_hi, ksw_lo, vtile,
                                          Opart, Lpart);
    finalize_kernel<<<(NT * DY) / (256 * 8), 256, 0, stream>>>(Opart, Lpart, out);
}